// Round 1
// baseline (1014.284 us; speedup 1.0000x reference)
//
#include <hip/hip_runtime.h>

// Problem constants (B,N,T,F,H,R) = (32,1024,32,5,64,5)
constexpr int Bc = 32, Nc = 1024, Tc = 32, Fc = 5, Hc = 64;
constexpr int BNc = Bc * Nc;   // 32768 sequences
constexpr int G4H = 4 * Hc;    // 256 gate rows

#define DEVFN __device__ __forceinline__

DEVFN float sigm(float x) { return 1.f / (1.f + __expf(-x)); }
// tanh via exp; safe at +/-inf: 1 - 2/(e^{2x}+1)
DEVFN float tanh_fast(float x) { return 1.f - 2.f / (__expf(2.f * x) + 1.f); }

// ---------------- Kernel 1: fused LSTM + temporal attention -----------------
// grid: BN/16 blocks of 256 threads (4 waves); each wave processes 4 sequences.
// Lane L owns hidden unit L: computes gates i,f,g,o for unit L (j = g*64+L),
// so the c/h update is lane-local. h broadcast via LDS; Whh^T staged in LDS
// with pitch 257 (conflict-free staging writes AND main-loop reads).
// Attention uses online softmax (no hs history materialized).
__global__ __launch_bounds__(256) void lstm_attn_kernel(
    const float* __restrict__ x,      // [BN, T, F]
    const float* __restrict__ Wih,    // [4H, F]
    const float* __restrict__ Whh,    // [4H, H]
    const float* __restrict__ bih,    // [4H]
    const float* __restrict__ bhh,    // [4H]
    const float* __restrict__ attn_w, // [H]
    const float* __restrict__ attn_b, // [1]
    float* __restrict__ e_old)        // [BN, H]
{
    constexpr int WP = 257;                 // odd pitch -> bank-stride 1
    __shared__ float WhhT[Hc * WP];         // [k][j]
    __shared__ float hb[16][Hc];            // per-seq hidden state
    __shared__ float xb[16][Tc * Fc];       // per-seq input window

    const int tid  = threadIdx.x;
    const int wave = tid >> 6;
    const int lane = tid & 63;

    // stage Whh^T : read coalesced (idx = j*64+k), write addr k*257+j
    for (int idx = tid; idx < G4H * Hc; idx += 256) {
        int j = idx >> 6, k = idx & 63;
        WhhT[k * WP + j] = Whh[idx];
    }
    // stage x for the block's 16 sequences (coalesced)
    for (int idx = tid; idx < 16 * Tc * Fc; idx += 256) {
        (&xb[0][0])[idx] = x[blockIdx.x * (16 * Tc * Fc) + idx];
    }
    // per-lane input-projection weights: Wih rows g*64+lane, f=0..4
    float wih[4][Fc], bias[4];
    #pragma unroll
    for (int g = 0; g < 4; ++g) {
        int j = g * 64 + lane;
        #pragma unroll
        for (int f = 0; f < Fc; ++f) wih[g][f] = Wih[j * Fc + f];
        bias[g] = bih[j] + bhh[j];
    }
    const float awl = attn_w[lane];
    const float ab  = attn_b[0];

    float c[4]    = {0.f, 0.f, 0.f, 0.f};
    float oac[4]  = {0.f, 0.f, 0.f, 0.f};
    float mrun[4] = {-1e30f, -1e30f, -1e30f, -1e30f};
    float lrun[4] = {0.f, 0.f, 0.f, 0.f};
    #pragma unroll
    for (int s = 0; s < 4; ++s) hb[wave * 4 + s][lane] = 0.f;
    __syncthreads();

    for (int t = 0; t < Tc; ++t) {
        float acc[4][4];
        // input projection + bias
        #pragma unroll
        for (int s = 0; s < 4; ++s) {
            float xv[Fc];
            #pragma unroll
            for (int f = 0; f < Fc; ++f) xv[f] = xb[wave * 4 + s][t * Fc + f];
            #pragma unroll
            for (int g = 0; g < 4; ++g) {
                float a = bias[g];
                #pragma unroll
                for (int f = 0; f < Fc; ++f) a += xv[f] * wih[g][f];
                acc[s][g] = a;
            }
        }
        // recurrent matvec: gates[j] += sum_k h[k] * Whh[j][k]
        #pragma unroll 4
        for (int k = 0; k < Hc; ++k) {
            float w0 = WhhT[k * WP +   0 + lane];
            float w1 = WhhT[k * WP +  64 + lane];
            float w2 = WhhT[k * WP + 128 + lane];
            float w3 = WhhT[k * WP + 192 + lane];
            #pragma unroll
            for (int s = 0; s < 4; ++s) {
                float hv = hb[wave * 4 + s][k];
                acc[s][0] += hv * w0; acc[s][1] += hv * w1;
                acc[s][2] += hv * w2; acc[s][3] += hv * w3;
            }
        }
        // LSTM cell update (torch gate order i,f,g,o)
        float hnew[4];
        #pragma unroll
        for (int s = 0; s < 4; ++s) {
            float ig = sigm(acc[s][0]);
            float fg = sigm(acc[s][1]);
            float gg = tanh_fast(acc[s][2]);
            float og = sigm(acc[s][3]);
            c[s] = fg * c[s] + ig * gg;
            hnew[s] = og * tanh_fast(c[s]);
        }
        __syncthreads();                       // old h fully consumed
        #pragma unroll
        for (int s = 0; s < 4; ++s) hb[wave * 4 + s][lane] = hnew[s];
        __syncthreads();                       // new h visible
        // attention: score_t = tanh(h . attn_w + b); online softmax accum
        #pragma unroll
        for (int s = 0; s < 4; ++s) {
            float part = hnew[s] * awl;
            #pragma unroll
            for (int off = 32; off; off >>= 1) part += __shfl_xor(part, off);
            float sc = tanh_fast(part + ab);
            float mn = fmaxf(mrun[s], sc);
            float scale = __expf(mrun[s] - mn);
            float e = __expf(sc - mn);
            lrun[s] = lrun[s] * scale + e;
            oac[s]  = oac[s]  * scale + e * hnew[s];
            mrun[s] = mn;
        }
    }
    const int seq0 = blockIdx.x * 16 + wave * 4;
    #pragma unroll
    for (int s = 0; s < 4; ++s)
        e_old[(seq0 + s) * Hc + lane] = oac[s] / lrun[s];
}

// ---------------- Kernel 2: edge coefficients + inverse degree --------------
// block = one row i; coef[i][j] = mask * leaky_relu(A[i,j,:].gnn_w + b, 0.2);
// rdeg[i] = 1 / (#j with sum(A[i,j,:]) > 0)
__global__ __launch_bounds__(256) void coef_kernel(
    const float* __restrict__ A,     // [N, N, R]
    const float* __restrict__ gnn_w, // [R]
    const float* __restrict__ gnn_b, // [1]
    float* __restrict__ coef,        // [N, N]
    float* __restrict__ rdeg)        // [N]
{
    const int i = blockIdx.x;
    const int tid = threadIdx.x;
    float gw[Fc];
    #pragma unroll
    for (int f = 0; f < Fc; ++f) gw[f] = gnn_w[f];
    const float gb = gnn_b[0];
    float cnt = 0.f;
    for (int j = tid; j < Nc; j += 256) {
        const float* a = A + ((size_t)i * Nc + j) * Fc;
        float s = 0.f, d = 0.f;
        #pragma unroll
        for (int f = 0; f < Fc; ++f) { float v = a[f]; s += v; d += v * gw[f]; }
        d += gb;
        float w = d >= 0.f ? d : 0.2f * d;
        float m = s > 0.f ? 1.f : 0.f;
        coef[(size_t)i * Nc + j] = m * w;
        cnt += m;
    }
    #pragma unroll
    for (int off = 32; off; off >>= 1) cnt += __shfl_xor(cnt, off);
    __shared__ float red[4];
    if ((tid & 63) == 0) red[tid >> 6] = cnt;
    __syncthreads();
    if (tid == 0) rdeg[i] = 1.0f / (red[0] + red[1] + red[2] + red[3]);
}

// ---------------- Kernel 3: fused GNN message pass + prediction head --------
// block = (batch b, 64-row i-tile). Flash-style over j-tiles:
//   S = Ei . Ej^T  (64x64, K=64) ; P = S * coef ; O += P . Ej  (64x64, K=64)
// epilogue: preds[b,i] = e_old[i].pw[0:64] + (O[i]*rdeg[i]).pw[64:128] + pb
__global__ __launch_bounds__(256) void gnn_pred_kernel(
    const float* __restrict__ e_old,  // [B*N, H]
    const float* __restrict__ coef,   // [N, N]
    const float* __restrict__ rdeg,   // [N]
    const float* __restrict__ pred_w, // [2H]
    const float* __restrict__ pred_b, // [1]
    float* __restrict__ preds)        // [B*N]
{
    constexpr int PP = 68;            // padded pitch (float4-aligned)
    __shared__ float EiT[Hc * PP];    // [h][i]
    __shared__ float EjT[Hc * PP];    // [h][j]
    __shared__ float Ej2[64 * PP];    // [j][h]
    __shared__ float PT [64 * PP];    // [j][i]
    __shared__ float pacc[64];

    const int b   = blockIdx.x >> 4;
    const int it  = blockIdx.x & 15;
    const int tid = threadIdx.x;
    const int ix = tid & 15, jx = tid >> 4;   // 16x16 thread grid
    const int i0 = 4 * ix, j0 = 4 * jx;       // j0 doubles as h0 in O-gemm
    const float* Eb = e_old + (size_t)b * Nc * Hc;

    // stage Ei tile transposed
    for (int rep = 0; rep < 4; ++rep) {
        int flat = rep * 1024 + tid * 4;
        int r = flat >> 6, h = flat & 63;
        float4 v = *(const float4*)(Eb + (size_t)(it * 64 + r) * Hc + h);
        EiT[(h + 0) * PP + r] = v.x;
        EiT[(h + 1) * PP + r] = v.y;
        EiT[(h + 2) * PP + r] = v.z;
        EiT[(h + 3) * PP + r] = v.w;
    }
    if (tid < 64) pacc[tid] = 0.f;

    float O[4][4] = {};
    float pwl[4], pwh[4];
    #pragma unroll
    for (int e2 = 0; e2 < 4; ++e2) {
        pwl[e2] = pred_w[j0 + e2];
        pwh[e2] = pred_w[64 + j0 + e2];
    }
    __syncthreads();

    for (int jt = 0; jt < 16; ++jt) {
        // stage Ej tile (both layouts)
        for (int rep = 0; rep < 4; ++rep) {
            int flat = rep * 1024 + tid * 4;
            int r = flat >> 6, h = flat & 63;
            float4 v = *(const float4*)(Eb + (size_t)(jt * 64 + r) * Hc + h);
            *(float4*)(&Ej2[r * PP + h]) = v;
            EjT[(h + 0) * PP + r] = v.x;
            EjT[(h + 1) * PP + r] = v.y;
            EjT[(h + 2) * PP + r] = v.z;
            EjT[(h + 3) * PP + r] = v.w;
        }
        __syncthreads();

        // S = Ei . Ej^T (per-thread 4x4 tile)
        float S[4][4] = {};
        for (int h = 0; h < 64; ++h) {
            float4 av = *(const float4*)(&EiT[h * PP + i0]);
            float4 bv = *(const float4*)(&EjT[h * PP + j0]);
            float aa[4] = {av.x, av.y, av.z, av.w};
            float bb[4] = {bv.x, bv.y, bv.z, bv.w};
            #pragma unroll
            for (int r = 0; r < 4; ++r)
                #pragma unroll
                for (int cc = 0; cc < 4; ++cc)
                    S[r][cc] += aa[r] * bb[cc];
        }
        // P = S * coef ; store transposed for O-gemm
        #pragma unroll
        for (int r = 0; r < 4; ++r) {
            int gi = it * 64 + i0 + r;
            float4 cf = *(const float4*)(&coef[(size_t)gi * Nc + jt * 64 + j0]);
            S[r][0] *= cf.x; S[r][1] *= cf.y; S[r][2] *= cf.z; S[r][3] *= cf.w;
        }
        #pragma unroll
        for (int r = 0; r < 4; ++r)
            #pragma unroll
            for (int cc = 0; cc < 4; ++cc)
                PT[(j0 + cc) * PP + i0 + r] = S[r][cc];
        __syncthreads();

        // O += P . Ej   (thread tile = i0..3 x h0..3 with h0 = j0)
        for (int j = 0; j < 64; ++j) {
            float4 pv = *(const float4*)(&PT[j * PP + i0]);
            float4 ev = *(const float4*)(&Ej2[j * PP + j0]);
            float pp[4] = {pv.x, pv.y, pv.z, pv.w};
            float ee[4] = {ev.x, ev.y, ev.z, ev.w};
            #pragma unroll
            for (int r = 0; r < 4; ++r)
                #pragma unroll
                for (int cc = 0; cc < 4; ++cc)
                    O[r][cc] += pp[r] * ee[cc];
        }
        __syncthreads();   // before next tile overwrites Ej/PT
    }

    // epilogue: pred partial dot, reduced across h-groups via LDS atomics
    #pragma unroll
    for (int r = 0; r < 4; ++r) {
        int gi = it * 64 + i0 + r;
        float rd = rdeg[gi];
        float part = 0.f;
        #pragma unroll
        for (int cc = 0; cc < 4; ++cc) {
            part += EiT[(j0 + cc) * PP + i0 + r] * pwl[cc];   // e_old half
            part += O[r][cc] * rd * pwh[cc];                  // e_new half
        }
        atomicAdd(&pacc[i0 + r], part);
    }
    __syncthreads();
    if (tid < 64)
        preds[(size_t)b * Nc + it * 64 + tid] = pacc[tid] + pred_b[0];
}

extern "C" void kernel_launch(void* const* d_in, const int* in_sizes, int n_in,
                              void* d_out, int out_size, void* d_ws, size_t ws_size,
                              hipStream_t stream) {
    const float* x      = (const float*)d_in[0];
    const float* A      = (const float*)d_in[1];
    const float* Wih    = (const float*)d_in[2];
    const float* Whh    = (const float*)d_in[3];
    const float* bih    = (const float*)d_in[4];
    const float* bhh    = (const float*)d_in[5];
    const float* attn_w = (const float*)d_in[6];
    const float* attn_b = (const float*)d_in[7];
    const float* gnn_w  = (const float*)d_in[8];
    const float* gnn_b  = (const float*)d_in[9];
    const float* pred_w = (const float*)d_in[10];
    const float* pred_b = (const float*)d_in[11];
    float* preds = (float*)d_out;

    // workspace layout (fp32): e_old [BN*H] | coef [N*N] | rdeg [N]  (~12 MB)
    float* e_old = (float*)d_ws;
    float* coef  = e_old + (size_t)BNc * Hc;
    float* rdeg  = coef + (size_t)Nc * Nc;

    lstm_attn_kernel<<<BNc / 16, 256, 0, stream>>>(x, Wih, Whh, bih, bhh,
                                                   attn_w, attn_b, e_old);
    coef_kernel<<<Nc, 256, 0, stream>>>(A, gnn_w, gnn_b, coef, rdeg);
    gnn_pred_kernel<<<Bc * (Nc / 64), 256, 0, stream>>>(e_old, coef, rdeg,
                                                        pred_w, pred_b, preds);
}

// Round 2
// 331.738 us; speedup vs baseline: 3.0575x; 3.0575x over previous
//
#include <hip/hip_runtime.h>

// Problem constants (B,N,T,F,H,R) = (32,1024,32,5,64,5)
constexpr int Bc = 32, Nc = 1024, Tc = 32, Fc = 5, Hc = 64;
constexpr int BNc = Bc * Nc;   // 32768 sequences
constexpr int G4H = 4 * Hc;    // 256 gate rows

#define DEVFN __device__ __forceinline__

typedef _Float16 f16x8 __attribute__((ext_vector_type(8)));
typedef float    f32x16 __attribute__((ext_vector_type(16)));

DEVFN float fast_rcp(float x) { return __builtin_amdgcn_rcpf(x); }
DEVFN float sigm(float x) { return fast_rcp(1.f + __expf(-x)); }
// tanh = 1 - 2/(e^{2x}+1); correct at +/-inf
DEVFN float tanh_fast(float x) { return 1.f - 2.f * fast_rcp(__expf(2.f * x) + 1.f); }

// ---------------- Kernel 1: fused LSTM + temporal attention (MFMA) ----------
// grid 256 blocks x 256 thr. Block = 128 seqs; wave = 32 seqs (m = lane&31).
// GEMM per t: D[j][m] = W'[j][k] * Bh[k][m], K'=80 = [Whh(64) | Wih(5) | bias | pad]
// via mfma_f32_32x32x16_f16, A (=W') resident in 160 VGPRs, D rows = gate idx.
// Lane (m = lane&31, hi = lane>>5) owns units u with (u&7)>>2 == hi:
//   u = 8a + 4*hi + p  (a=0..7, p=0..3), tile jt = 2g + (a>>2), reg = p + 4*(a&3).
// B frag for k-tile kt (k = 16kt + 8hi + e): half own h, half from lane^32.
__global__ __launch_bounds__(256, 1) void lstm_attn_kernel(
    const float* __restrict__ x,      // [BN, T, F]
    const float* __restrict__ Wih,    // [4H, F]
    const float* __restrict__ Whh,    // [4H, H]
    const float* __restrict__ bih,    // [4H]
    const float* __restrict__ bhh,    // [4H]
    const float* __restrict__ attn_w, // [H]
    const float* __restrict__ attn_b, // [1]
    float* __restrict__ e_old)        // [BN, H]
{
    constexpr int XP = 164;                         // x pitch in halfs (2-way free)
    __shared__ __align__(16) char smem[128 * XP * 2]; // 42 KB; aliased xs / es
    _Float16* xs = (_Float16*)smem;                 // [128][XP] fp16 x
    float*    es = (float*)smem;                    // [128][65] epilogue bounce

    const int tid  = threadIdx.x;
    const int wave = tid >> 6;
    const int lane = tid & 63;
    const int l31  = lane & 31;
    const int hi   = lane >> 5;

    // ---- stage x (fp32 global -> fp16 LDS, pitch XP) ----
    const float* xg = x + (size_t)blockIdx.x * 128 * Tc * Fc;
    for (int i = tid; i < 128 * Tc * Fc; i += 256) {
        int m = i / 160, o = i - m * 160;
        xs[m * XP + o] = (_Float16)xg[i];
    }

    // ---- preload A fragments (W' in fp16): af[jt][kt], jt=0..7, kt=0..4 ----
    f16x8 af[8][5];
    #pragma unroll
    for (int jt = 0; jt < 8; ++jt) {
        const int j = 32 * jt + l31;
        #pragma unroll
        for (int kt = 0; kt < 4; ++kt) {
            const float* wp = Whh + j * 64 + kt * 16 + 8 * hi;
            float4 u0 = *(const float4*)wp;
            float4 u1 = *(const float4*)(wp + 4);
            af[jt][kt] = f16x8{(_Float16)u0.x, (_Float16)u0.y, (_Float16)u0.z, (_Float16)u0.w,
                               (_Float16)u1.x, (_Float16)u1.y, (_Float16)u1.z, (_Float16)u1.w};
        }
        // kt = 4 : rows 64..79 = [Wih(5) | bias | 0...]; hi==1 half is all zero
        float v[8];
        #pragma unroll
        for (int e = 0; e < 5; ++e) v[e] = Wih[j * Fc + e];
        v[5] = bih[j] + bhh[j]; v[6] = 0.f; v[7] = 0.f;
        #pragma unroll
        for (int e = 0; e < 8; ++e) {
            float z = hi ? 0.f : v[e];
            af[jt][4][e] = (_Float16)z;
        }
    }

    // attention weights for owned units
    float aw_own[32];
    #pragma unroll
    for (int a = 0; a < 8; ++a)
        #pragma unroll
        for (int p = 0; p < 4; ++p)
            aw_own[a * 4 + p] = attn_w[8 * a + 4 * hi + p];
    const float ab = attn_b[0];

    float hcur[32], cst[32], oacc[32];
    #pragma unroll
    for (int i = 0; i < 32; ++i) { hcur[i] = 0.f; cst[i] = 0.f; oacc[i] = 0.f; }
    float lsum = 0.f;

    f32x16 zero16 = {0,0,0,0,0,0,0,0,0,0,0,0,0,0,0,0};
    const int xrow = (wave * 32 + l31) * XP;
    __syncthreads();

    #pragma unroll 1
    for (int t = 0; t < Tc; ++t) {
        // ---- build B fragments ----
        f16x8 bf[5];
        #pragma unroll
        for (int kt = 0; kt < 4; ++kt) {
            float ownv[4], rcvv[4];
            #pragma unroll
            for (int p = 0; p < 4; ++p) {
                float own = hi ? hcur[(2 * kt + 1) * 4 + p] : hcur[(2 * kt) * 4 + p];
                float snd = hi ? hcur[(2 * kt) * 4 + p]     : hcur[(2 * kt + 1) * 4 + p];
                ownv[p] = own;
                rcvv[p] = __shfl_xor(snd, 32);
            }
            #pragma unroll
            for (int e = 0; e < 8; ++e) {
                float vv = ((e >> 2) == hi) ? ownv[e & 3] : rcvv[e & 3];
                bf[kt][e] = (_Float16)vv;
            }
        }
        {   // kt = 4 : [x0..x4, 1, 0, 0] on hi==0 half; zeros on hi==1
            float xv[8];
            #pragma unroll
            for (int e = 0; e < 5; ++e) xv[e] = (float)xs[xrow + t * Fc + e];
            xv[5] = 1.f; xv[6] = 0.f; xv[7] = 0.f;
            #pragma unroll
            for (int e = 0; e < 8; ++e) {
                float vv = hi ? 0.f : xv[e];
                bf[4][e] = (_Float16)vv;
            }
        }

        // ---- two half-passes over gate tiles (saves 64 acc VGPRs) ----
        #pragma unroll
        for (int h5 = 0; h5 < 2; ++h5) {
            f32x16 acc[4];
            #pragma unroll
            for (int g = 0; g < 4; ++g) {
                const int jt = 2 * g + h5;
                acc[g] = __builtin_amdgcn_mfma_f32_32x32x16_f16(af[jt][0], bf[0], zero16, 0, 0, 0);
                #pragma unroll
                for (int kt = 1; kt < 5; ++kt)
                    acc[g] = __builtin_amdgcn_mfma_f32_32x32x16_f16(af[jt][kt], bf[kt], acc[g], 0, 0, 0);
            }
            // cell update for the 16 owned units in this half (lane-local!)
            #pragma unroll
            for (int a2 = 0; a2 < 4; ++a2) {
                #pragma unroll
                for (int p = 0; p < 4; ++p) {
                    const int reg = p + 4 * a2;
                    const int ui  = (4 * h5 + a2) * 4 + p;
                    float ig = sigm(acc[0][reg]);
                    float fg = sigm(acc[1][reg]);
                    float gg = tanh_fast(acc[2][reg]);
                    float og = sigm(acc[3][reg]);
                    float cn = fmaf(fg, cst[ui], ig * gg);
                    cst[ui]  = cn;
                    hcur[ui] = og * tanh_fast(cn);
                }
            }
        }

        // ---- attention: score = tanh(h . aw + b); bounded -> no max tracking
        float part = 0.f;
        #pragma unroll
        for (int i = 0; i < 32; ++i) part = fmaf(hcur[i], aw_own[i], part);
        part += __shfl_xor(part, 32);
        float sc = tanh_fast(part + ab);
        float ew = __expf(sc);
        lsum += ew;
        #pragma unroll
        for (int i = 0; i < 32; ++i) oacc[i] = fmaf(ew, hcur[i], oacc[i]);
    }

    // ---- epilogue: e_old = oacc / lsum, via LDS bounce for coalesced stores
    __syncthreads();                    // xs dead everywhere before aliasing
    const float li = 1.f / lsum;
    const int   mrow = wave * 32 + l31;
    #pragma unroll
    for (int a = 0; a < 8; ++a)
        #pragma unroll
        for (int p = 0; p < 4; ++p)
            es[mrow * 65 + 8 * a + 4 * hi + p] = oacc[a * 4 + p] * li;
    __syncthreads();
    float* eg = e_old + (size_t)blockIdx.x * 128 * Hc;
    for (int i = tid; i < 128 * Hc; i += 256) {
        int m = i >> 6, u = i & 63;
        eg[i] = es[m * 65 + u];
    }
}

// ---------------- Kernel 2: edge coefficients + inverse degree --------------
__global__ __launch_bounds__(256) void coef_kernel(
    const float* __restrict__ A,     // [N, N, R]
    const float* __restrict__ gnn_w, // [R]
    const float* __restrict__ gnn_b, // [1]
    float* __restrict__ coef,        // [N, N]
    float* __restrict__ rdeg)        // [N]
{
    const int i = blockIdx.x;
    const int tid = threadIdx.x;
    float gw[Fc];
    #pragma unroll
    for (int f = 0; f < Fc; ++f) gw[f] = gnn_w[f];
    const float gb = gnn_b[0];
    float cnt = 0.f;
    for (int j = tid; j < Nc; j += 256) {
        const float* a = A + ((size_t)i * Nc + j) * Fc;
        float s = 0.f, d = 0.f;
        #pragma unroll
        for (int f = 0; f < Fc; ++f) { float v = a[f]; s += v; d += v * gw[f]; }
        d += gb;
        float w = d >= 0.f ? d : 0.2f * d;
        float m = s > 0.f ? 1.f : 0.f;
        coef[(size_t)i * Nc + j] = m * w;
        cnt += m;
    }
    #pragma unroll
    for (int off = 32; off; off >>= 1) cnt += __shfl_xor(cnt, off);
    __shared__ float red[4];
    if ((tid & 63) == 0) red[tid >> 6] = cnt;
    __syncthreads();
    if (tid == 0) rdeg[i] = 1.0f / (red[0] + red[1] + red[2] + red[3]);
}

// ---------------- Kernel 3: fused GNN message pass + prediction head --------
__global__ __launch_bounds__(256) void gnn_pred_kernel(
    const float* __restrict__ e_old,  // [B*N, H]
    const float* __restrict__ coef,   // [N, N]
    const float* __restrict__ rdeg,   // [N]
    const float* __restrict__ pred_w, // [2H]
    const float* __restrict__ pred_b, // [1]
    float* __restrict__ preds)        // [B*N]
{
    constexpr int PP = 68;            // padded pitch (float4-aligned)
    __shared__ float EiT[Hc * PP];    // [h][i]
    __shared__ float EjT[Hc * PP];    // [h][j]
    __shared__ float Ej2[64 * PP];    // [j][h]
    __shared__ float PT [64 * PP];    // [j][i]
    __shared__ float pacc[64];

    const int b   = blockIdx.x >> 4;
    const int it  = blockIdx.x & 15;
    const int tid = threadIdx.x;
    const int ix = tid & 15, jx = tid >> 4;   // 16x16 thread grid
    const int i0 = 4 * ix, j0 = 4 * jx;       // j0 doubles as h0 in O-gemm
    const float* Eb = e_old + (size_t)b * Nc * Hc;

    for (int rep = 0; rep < 4; ++rep) {
        int flat = rep * 1024 + tid * 4;
        int r = flat >> 6, h = flat & 63;
        float4 v = *(const float4*)(Eb + (size_t)(it * 64 + r) * Hc + h);
        EiT[(h + 0) * PP + r] = v.x;
        EiT[(h + 1) * PP + r] = v.y;
        EiT[(h + 2) * PP + r] = v.z;
        EiT[(h + 3) * PP + r] = v.w;
    }
    if (tid < 64) pacc[tid] = 0.f;

    float O[4][4] = {};
    float pwl[4], pwh[4];
    #pragma unroll
    for (int e2 = 0; e2 < 4; ++e2) {
        pwl[e2] = pred_w[j0 + e2];
        pwh[e2] = pred_w[64 + j0 + e2];
    }
    __syncthreads();

    for (int jt = 0; jt < 16; ++jt) {
        for (int rep = 0; rep < 4; ++rep) {
            int flat = rep * 1024 + tid * 4;
            int r = flat >> 6, h = flat & 63;
            float4 v = *(const float4*)(Eb + (size_t)(jt * 64 + r) * Hc + h);
            *(float4*)(&Ej2[r * PP + h]) = v;
            EjT[(h + 0) * PP + r] = v.x;
            EjT[(h + 1) * PP + r] = v.y;
            EjT[(h + 2) * PP + r] = v.z;
            EjT[(h + 3) * PP + r] = v.w;
        }
        __syncthreads();

        float S[4][4] = {};
        for (int h = 0; h < 64; ++h) {
            float4 av = *(const float4*)(&EiT[h * PP + i0]);
            float4 bv = *(const float4*)(&EjT[h * PP + j0]);
            float aa[4] = {av.x, av.y, av.z, av.w};
            float bb[4] = {bv.x, bv.y, bv.z, bv.w};
            #pragma unroll
            for (int r = 0; r < 4; ++r)
                #pragma unroll
                for (int cc = 0; cc < 4; ++cc)
                    S[r][cc] += aa[r] * bb[cc];
        }
        #pragma unroll
        for (int r = 0; r < 4; ++r) {
            int gi = it * 64 + i0 + r;
            float4 cf = *(const float4*)(&coef[(size_t)gi * Nc + jt * 64 + j0]);
            S[r][0] *= cf.x; S[r][1] *= cf.y; S[r][2] *= cf.z; S[r][3] *= cf.w;
        }
        #pragma unroll
        for (int r = 0; r < 4; ++r)
            #pragma unroll
            for (int cc = 0; cc < 4; ++cc)
                PT[(j0 + cc) * PP + i0 + r] = S[r][cc];
        __syncthreads();

        for (int j = 0; j < 64; ++j) {
            float4 pv = *(const float4*)(&PT[j * PP + i0]);
            float4 ev = *(const float4*)(&Ej2[j * PP + j0]);
            float pp[4] = {pv.x, pv.y, pv.z, pv.w};
            float ee[4] = {ev.x, ev.y, ev.z, ev.w};
            #pragma unroll
            for (int r = 0; r < 4; ++r)
                #pragma unroll
                for (int cc = 0; cc < 4; ++cc)
                    O[r][cc] += pp[r] * ee[cc];
        }
        __syncthreads();
    }

    #pragma unroll
    for (int r = 0; r < 4; ++r) {
        int gi = it * 64 + i0 + r;
        float rd = rdeg[gi];
        float part = 0.f;
        #pragma unroll
        for (int cc = 0; cc < 4; ++cc) {
            part += EiT[(j0 + cc) * PP + i0 + r] * pwl[cc];
            part += O[r][cc] * rd * pwh[cc];
        }
        atomicAdd(&pacc[i0 + r], part);
    }
    __syncthreads();
    if (tid < 64)
        preds[(size_t)b * Nc + it * 64 + tid] = pacc[tid] + pred_b[0];
}

extern "C" void kernel_launch(void* const* d_in, const int* in_sizes, int n_in,
                              void* d_out, int out_size, void* d_ws, size_t ws_size,
                              hipStream_t stream) {
    const float* x      = (const float*)d_in[0];
    const float* A      = (const float*)d_in[1];
    const float* Wih    = (const float*)d_in[2];
    const float* Whh    = (const float*)d_in[3];
    const float* bih    = (const float*)d_in[4];
    const float* bhh    = (const float*)d_in[5];
    const float* attn_w = (const float*)d_in[6];
    const float* attn_b = (const float*)d_in[7];
    const float* gnn_w  = (const float*)d_in[8];
    const float* gnn_b  = (const float*)d_in[9];
    const float* pred_w = (const float*)d_in[10];
    const float* pred_b = (const float*)d_in[11];
    float* preds = (float*)d_out;

    // workspace layout (fp32): e_old [BN*H] | coef [N*N] | rdeg [N]  (~12 MB)
    float* e_old = (float*)d_ws;
    float* coef  = e_old + (size_t)BNc * Hc;
    float* rdeg  = coef + (size_t)Nc * Nc;

    lstm_attn_kernel<<<BNc / 128, 256, 0, stream>>>(x, Wih, Whh, bih, bhh,
                                                    attn_w, attn_b, e_old);
    coef_kernel<<<Nc, 256, 0, stream>>>(A, gnn_w, gnn_b, coef, rdeg);
    gnn_pred_kernel<<<Bc * (Nc / 64), 256, 0, stream>>>(e_old, coef, rdeg,
                                                        pred_w, pred_b, preds);
}

// Round 3
// 274.002 us; speedup vs baseline: 3.7017x; 1.2107x over previous
//
#include <hip/hip_runtime.h>

// Problem constants (B,N,T,F,H,R) = (32,1024,32,5,64,5)
constexpr int Bc = 32, Nc = 1024, Tc = 32, Fc = 5, Hc = 64;
constexpr int BNc = Bc * Nc;   // 32768 sequences
constexpr int G4H = 4 * Hc;    // 256 gate rows

#define DEVFN __device__ __forceinline__

typedef _Float16 f16x8 __attribute__((ext_vector_type(8)));
typedef float    f32x16 __attribute__((ext_vector_type(16)));

DEVFN float fast_rcp(float x) { return __builtin_amdgcn_rcpf(x); }
DEVFN float sigm(float x) { return fast_rcp(1.f + __expf(-x)); }
DEVFN float tanh_fast(float x) { return 1.f - 2.f * fast_rcp(__expf(2.f * x) + 1.f); }

// ---------------- Kernel 1: fused LSTM + temporal attention (MFMA) ----------
// Unchanged core from round 2; epilogue now emits fp16 E16 (row-major) and
// ET (transposed) for the MFMA GNN instead of f32 e_old.
__global__ __launch_bounds__(256, 1) void lstm_attn_kernel(
    const float* __restrict__ x,      // [BN, T, F]
    const float* __restrict__ Wih,    // [4H, F]
    const float* __restrict__ Whh,    // [4H, H]
    const float* __restrict__ bih,    // [4H]
    const float* __restrict__ bhh,    // [4H]
    const float* __restrict__ attn_w, // [H]
    const float* __restrict__ attn_b, // [1]
    _Float16* __restrict__ E16,       // [B*N, H] fp16 row-major
    _Float16* __restrict__ ET)        // [B][H][N] fp16 transposed
{
    constexpr int XP = 164;
    __shared__ __align__(16) char smem[128 * XP * 2]; // 42 KB; aliased xs / es
    _Float16* xs = (_Float16*)smem;                 // [128][XP] fp16 x
    float*    es = (float*)smem;                    // [128][65] epilogue bounce

    const int tid  = threadIdx.x;
    const int wave = tid >> 6;
    const int lane = tid & 63;
    const int l31  = lane & 31;
    const int hi   = lane >> 5;

    const float* xg = x + (size_t)blockIdx.x * 128 * Tc * Fc;
    for (int i = tid; i < 128 * Tc * Fc; i += 256) {
        int m = i / 160, o = i - m * 160;
        xs[m * XP + o] = (_Float16)xg[i];
    }

    f16x8 af[8][5];
    #pragma unroll
    for (int jt = 0; jt < 8; ++jt) {
        const int j = 32 * jt + l31;
        #pragma unroll
        for (int kt = 0; kt < 4; ++kt) {
            const float* wp = Whh + j * 64 + kt * 16 + 8 * hi;
            float4 u0 = *(const float4*)wp;
            float4 u1 = *(const float4*)(wp + 4);
            af[jt][kt] = f16x8{(_Float16)u0.x, (_Float16)u0.y, (_Float16)u0.z, (_Float16)u0.w,
                               (_Float16)u1.x, (_Float16)u1.y, (_Float16)u1.z, (_Float16)u1.w};
        }
        float v[8];
        #pragma unroll
        for (int e = 0; e < 5; ++e) v[e] = Wih[j * Fc + e];
        v[5] = bih[j] + bhh[j]; v[6] = 0.f; v[7] = 0.f;
        #pragma unroll
        for (int e = 0; e < 8; ++e) {
            float z = hi ? 0.f : v[e];
            af[jt][4][e] = (_Float16)z;
        }
    }

    float aw_own[32];
    #pragma unroll
    for (int a = 0; a < 8; ++a)
        #pragma unroll
        for (int p = 0; p < 4; ++p)
            aw_own[a * 4 + p] = attn_w[8 * a + 4 * hi + p];
    const float ab = attn_b[0];

    float hcur[32], cst[32], oacc[32];
    #pragma unroll
    for (int i = 0; i < 32; ++i) { hcur[i] = 0.f; cst[i] = 0.f; oacc[i] = 0.f; }
    float lsum = 0.f;

    f32x16 zero16 = {0,0,0,0,0,0,0,0,0,0,0,0,0,0,0,0};
    const int xrow = (wave * 32 + l31) * XP;
    __syncthreads();

    #pragma unroll 1
    for (int t = 0; t < Tc; ++t) {
        f16x8 bf[5];
        #pragma unroll
        for (int kt = 0; kt < 4; ++kt) {
            float ownv[4], rcvv[4];
            #pragma unroll
            for (int p = 0; p < 4; ++p) {
                float own = hi ? hcur[(2 * kt + 1) * 4 + p] : hcur[(2 * kt) * 4 + p];
                float snd = hi ? hcur[(2 * kt) * 4 + p]     : hcur[(2 * kt + 1) * 4 + p];
                ownv[p] = own;
                rcvv[p] = __shfl_xor(snd, 32);
            }
            #pragma unroll
            for (int e = 0; e < 8; ++e) {
                float vv = ((e >> 2) == hi) ? ownv[e & 3] : rcvv[e & 3];
                bf[kt][e] = (_Float16)vv;
            }
        }
        {
            float xv[8];
            #pragma unroll
            for (int e = 0; e < 5; ++e) xv[e] = (float)xs[xrow + t * Fc + e];
            xv[5] = 1.f; xv[6] = 0.f; xv[7] = 0.f;
            #pragma unroll
            for (int e = 0; e < 8; ++e) {
                float vv = hi ? 0.f : xv[e];
                bf[4][e] = (_Float16)vv;
            }
        }

        #pragma unroll
        for (int h5 = 0; h5 < 2; ++h5) {
            f32x16 acc[4];
            #pragma unroll
            for (int g = 0; g < 4; ++g) {
                const int jt = 2 * g + h5;
                acc[g] = __builtin_amdgcn_mfma_f32_32x32x16_f16(af[jt][0], bf[0], zero16, 0, 0, 0);
                #pragma unroll
                for (int kt = 1; kt < 5; ++kt)
                    acc[g] = __builtin_amdgcn_mfma_f32_32x32x16_f16(af[jt][kt], bf[kt], acc[g], 0, 0, 0);
            }
            #pragma unroll
            for (int a2 = 0; a2 < 4; ++a2) {
                #pragma unroll
                for (int p = 0; p < 4; ++p) {
                    const int reg = p + 4 * a2;
                    const int ui  = (4 * h5 + a2) * 4 + p;
                    float ig = sigm(acc[0][reg]);
                    float fg = sigm(acc[1][reg]);
                    float gg = tanh_fast(acc[2][reg]);
                    float og = sigm(acc[3][reg]);
                    float cn = fmaf(fg, cst[ui], ig * gg);
                    cst[ui]  = cn;
                    hcur[ui] = og * tanh_fast(cn);
                }
            }
        }

        float part = 0.f;
        #pragma unroll
        for (int i = 0; i < 32; ++i) part = fmaf(hcur[i], aw_own[i], part);
        part += __shfl_xor(part, 32);
        float sc = tanh_fast(part + ab);
        float ew = __expf(sc);
        lsum += ew;
        #pragma unroll
        for (int i = 0; i < 32; ++i) oacc[i] = fmaf(ew, hcur[i], oacc[i]);
    }

    // ---- epilogue: bounce to LDS, emit E16 + ET (fp16) ----
    __syncthreads();                    // xs dead before aliasing
    const float li = 1.f / lsum;
    const int   mrow = wave * 32 + l31;
    #pragma unroll
    for (int a = 0; a < 8; ++a)
        #pragma unroll
        for (int p = 0; p < 4; ++p)
            es[mrow * 65 + 8 * a + 4 * hi + p] = oacc[a * 4 + p] * li;
    __syncthreads();

    uint* E16u = (uint*)E16 + (size_t)blockIdx.x * 128 * 32;
    for (int idx = tid; idx < 128 * 32; idx += 256) {
        int m = idx >> 5, hp = idx & 31;
        union { _Float16 h[2]; uint u; } cv;
        cv.h[0] = (_Float16)es[m * 65 + 2 * hp];
        cv.h[1] = (_Float16)es[m * 65 + 2 * hp + 1];
        E16u[idx] = cv.u;
    }
    const int bb_ = blockIdx.x >> 3, n0c = (blockIdx.x & 7) * 64;
    uint* ETu = (uint*)ET;
    for (int idx = tid; idx < 64 * 64; idx += 256) {
        int h = idx >> 6, c = idx & 63;
        union { _Float16 h2[2]; uint u; } cv;
        cv.h2[0] = (_Float16)es[(2 * c) * 65 + h];
        cv.h2[1] = (_Float16)es[(2 * c + 1) * 65 + h];
        ETu[((size_t)bb_ * 64 + h) * 512 + n0c + c] = cv.u;
    }
}

// ---------------- Kernel 2: edge coefficients (packed) + degree -------------
// coefQ layout: [(j>>2)][i][j&3] f32 so gnn lanes can dwordx4 4 j-regs at once.
// deg accumulated via float atomicAdd of integer counts (exact).
__global__ __launch_bounds__(256) void coefq_kernel(
    const float* __restrict__ A,     // [N, N, R]
    const float* __restrict__ gnn_w, // [R]
    const float* __restrict__ gnn_b, // [1]
    float* __restrict__ coefQ,       // [N/4][N][4]
    float* __restrict__ deg)         // [N], pre-zeroed
{
    __shared__ float ct[64 * 68];
    const int t = threadIdx.x;
    const int it = blockIdx.x >> 4, jt = blockIdx.x & 15;
    const int i_loc = t >> 2, chunk = t & 3;
    float gw[5];
    #pragma unroll
    for (int f = 0; f < 5; ++f) gw[f] = gnn_w[f];
    const float gb = gnn_b[0];

    const float* Ab = A + ((size_t)(it * 64 + i_loc) * 1024 + jt * 64 + chunk * 16) * 5;
    float buf[80];
    #pragma unroll
    for (int k = 0; k < 20; ++k)
        *(float4*)&buf[4 * k] = ((const float4*)Ab)[k];

    float cnt = 0.f;
    #pragma unroll
    for (int jj = 0; jj < 16; ++jj) {
        float s = 0.f, d = gb;
        #pragma unroll
        for (int f = 0; f < 5; ++f) { float vv = buf[5 * jj + f]; s += vv; d = fmaf(vv, gw[f], d); }
        float cf = (s > 0.f) ? (d >= 0.f ? d : 0.2f * d) : 0.f;
        ct[i_loc * 68 + chunk * 16 + jj] = cf;
        cnt += (s > 0.f) ? 1.f : 0.f;
    }
    cnt += __shfl_xor(cnt, 1);
    cnt += __shfl_xor(cnt, 2);
    if ((t & 3) == 0) atomicAdd(&deg[it * 64 + i_loc], cnt);
    __syncthreads();

    const int i_o = t & 63;
    #pragma unroll
    for (int p = 0; p < 4; ++p) {
        int jg = (t >> 6) + 4 * p;
        float4 v = *(const float4*)&ct[i_o * 68 + 4 * jg];
        ((float4*)coefQ)[(size_t)(jt * 16 + jg) * 1024 + it * 64 + i_o] = v;
    }
}

// ---------------- Kernel 3: MFMA GNN message pass + prediction head ---------
// Block = (b, 64-row i-tile); 4 waves, each owns 4 private j-tiles.
// Per j-tile: S' = Ej.Ei^T (D[m=j][n=i]) -> P = S' * coefT (global dwordx4 from
// coefQ) -> shfl-convert P to A-layout -> O += P.Ej (via ET tile).
// LDS: XOR-swizzled fp16 tiles, wave-private (no barriers). Epilogue folds the
// pred head with shuffle reductions + global atomicAdd into zeroed preds.
__global__ __launch_bounds__(256, 2) void gnn_pred_kernel(
    const _Float16* __restrict__ E16,  // [B*N, H]
    const _Float16* __restrict__ ET,   // [B][H][N]
    const float* __restrict__ coefQ,   // [N/4][N][4]
    const float* __restrict__ deg,     // [N]
    const float* __restrict__ pred_w,  // [2H]
    const float* __restrict__ pred_b,  // [1]
    float* __restrict__ preds)         // [B*N], pre-zeroed
{
    __shared__ __align__(16) _Float16 tiles[2][4][64 * 64];  // 64 KB exactly
    const int tid  = threadIdx.x;
    const int w    = tid >> 6;
    const int lane = tid & 63;
    const int l31  = lane & 31;
    const int hi   = lane >> 5;
    const int b    = blockIdx.x >> 4;
    const int it   = blockIdx.x & 15;

    _Float16* EA = &tiles[0][w][0];    // Ej natural [j][h], swizzled chunks
    _Float16* EB = &tiles[1][w][0];    // Ej^T [h][j], swizzled chunks
    const float4* coefQ4 = (const float4*)coefQ;

    // Ei B-fragments, resident for the whole block (B[k=h][n=i])
    f16x8 eb[2][4];
    #pragma unroll
    for (int ni = 0; ni < 2; ++ni)
        #pragma unroll
        for (int kt = 0; kt < 4; ++kt)
            eb[ni][kt] = *(const f16x8*)(E16 +
                ((size_t)(b * 1024 + it * 64 + ni * 32 + l31) * 64 + 16 * kt + 8 * hi));

    f32x16 zero16 = {0,0,0,0,0,0,0,0,0,0,0,0,0,0,0,0};
    f32x16 oacc[2][2];
    #pragma unroll
    for (int mi = 0; mi < 2; ++mi)
        #pragma unroll
        for (int nh = 0; nh < 2; ++nh) oacc[mi][nh] = zero16;

    #pragma unroll 1
    for (int s = 0; s < 4; ++s) {
        const int jt = w * 4 + s;
        // ---- stage Ej (both layouts) into swizzled wave-private LDS ----
        const _Float16* srcA = E16 + (size_t)(b * 1024 + jt * 64) * 64;
        const _Float16* srcB = ET + (size_t)b * 64 * 1024 + jt * 64;
        #pragma unroll
        for (int q = 0; q < 8; ++q) {
            int f = q * 64 + lane, r = f >> 3, c = f & 7;
            uint4 va = *(const uint4*)(srcA + r * 64 + c * 8);
            *(uint4*)(EA + r * 64 + ((c ^ (r & 7)) * 8)) = va;
            uint4 vb = *(const uint4*)(srcB + r * 1024 + c * 8);
            *(uint4*)(EB + r * 64 + ((c ^ (r & 7)) * 8)) = vb;
        }
        // ---- S' = Ej . Ei^T ----
        f16x8 af[2][4];
        #pragma unroll
        for (int mj = 0; mj < 2; ++mj)
            #pragma unroll
            for (int kt = 0; kt < 4; ++kt)
                af[mj][kt] = *(const f16x8*)(EA + (mj * 32 + l31) * 64 +
                                             (((2 * kt + hi) ^ (l31 & 7)) * 8));
        f32x16 sacc[2][2];
        #pragma unroll
        for (int mj = 0; mj < 2; ++mj)
            #pragma unroll
            for (int ni = 0; ni < 2; ++ni) {
                f32x16 a = __builtin_amdgcn_mfma_f32_32x32x16_f16(af[mj][0], eb[ni][0], zero16, 0, 0, 0);
                #pragma unroll
                for (int kt = 1; kt < 4; ++kt)
                    a = __builtin_amdgcn_mfma_f32_32x32x16_f16(af[mj][kt], eb[ni][kt], a, 0, 0, 0);
                sacc[mj][ni] = a;
            }
        // ---- P = S' * coef (coefQ gather, fully coalesced dwordx4) ----
        float p[2][2][16];
        #pragma unroll
        for (int mj = 0; mj < 2; ++mj)
            #pragma unroll
            for (int ni = 0; ni < 2; ++ni)
                #pragma unroll
                for (int rg = 0; rg < 4; ++rg) {
                    int j0 = jt * 64 + mj * 32 + 8 * rg + 4 * hi;
                    float4 cf = coefQ4[(size_t)(j0 >> 2) * 1024 + it * 64 + ni * 32 + l31];
                    p[mj][ni][4 * rg + 0] = sacc[mj][ni][4 * rg + 0] * cf.x;
                    p[mj][ni][4 * rg + 1] = sacc[mj][ni][4 * rg + 1] * cf.y;
                    p[mj][ni][4 * rg + 2] = sacc[mj][ni][4 * rg + 2] * cf.z;
                    p[mj][ni][4 * rg + 3] = sacc[mj][ni][4 * rg + 3] * cf.w;
                }
        // ---- P (C-layout) -> fp16 A-frags via lane^32 exchange ----
        f16x8 pa[2][4];
        #pragma unroll
        for (int mi = 0; mi < 2; ++mi)
            #pragma unroll
            for (int ktj = 0; ktj < 4; ++ktj) {
                const int mj = ktj >> 1, rg = 2 * (ktj & 1);
                f16x8 fr;
                #pragma unroll
                for (int c4 = 0; c4 < 4; ++c4) {
                    float own_lo = p[mj][mi][rg * 4 + c4];
                    float own_hi = p[mj][mi][(rg + 1) * 4 + c4];
                    float send = hi ? own_lo : own_hi;
                    float recv = __shfl_xor(send, 32);
                    float lo = hi ? recv : own_lo;
                    float hv = hi ? own_hi : recv;
                    fr[c4]     = (_Float16)lo;
                    fr[4 + c4] = (_Float16)hv;
                }
                pa[mi][ktj] = fr;
            }
        // ---- O += P . Ej ----
        f16x8 bb[2][4];
        #pragma unroll
        for (int nh = 0; nh < 2; ++nh)
            #pragma unroll
            for (int ktj = 0; ktj < 4; ++ktj)
                bb[nh][ktj] = *(const f16x8*)(EB + (nh * 32 + l31) * 64 +
                                              (((2 * ktj + hi) ^ (l31 & 7)) * 8));
        #pragma unroll
        for (int mi = 0; mi < 2; ++mi)
            #pragma unroll
            for (int nh = 0; nh < 2; ++nh)
                #pragma unroll
                for (int ktj = 0; ktj < 4; ++ktj)
                    oacc[mi][nh] = __builtin_amdgcn_mfma_f32_32x32x16_f16(
                        pa[mi][ktj], bb[nh][ktj], oacc[mi][nh], 0, 0, 0);
    }

    // ---- epilogue: preds += rdeg[i] * sum_h O[i][h]*pwh[h]  (+ e_old part) --
    const float pwh0 = pred_w[64 + l31];
    const float pwh1 = pred_w[96 + l31];
    #pragma unroll
    for (int mi = 0; mi < 2; ++mi)
        #pragma unroll
        for (int r = 0; r < 16; ++r) {
            float v = oacc[mi][0][r] * pwh0 + oacc[mi][1][r] * pwh1;
            v += __shfl_xor(v, 1);  v += __shfl_xor(v, 2);  v += __shfl_xor(v, 4);
            v += __shfl_xor(v, 8);  v += __shfl_xor(v, 16);
            int i_loc = mi * 32 + 8 * (r >> 2) + (r & 3) + 4 * hi;
            int gi = it * 64 + i_loc;
            if (l31 == 0) {
                float dg = deg[gi];
                atomicAdd(&preds[b * 1024 + gi], v * fast_rcp(dg));
            }
        }
    if (w == 0) {
        const float pb0 = pred_b[0];
        #pragma unroll
        for (int ni = 0; ni < 2; ++ni) {
            float dot = 0.f;
            #pragma unroll
            for (int kt = 0; kt < 4; ++kt)
                #pragma unroll
                for (int e = 0; e < 8; ++e)
                    dot = fmaf((float)eb[ni][kt][e], pred_w[16 * kt + 8 * hi + e], dot);
            dot += __shfl_xor(dot, 32);
            if (hi == 0)
                atomicAdd(&preds[b * 1024 + it * 64 + ni * 32 + l31], dot + pb0);
        }
    }
}

extern "C" void kernel_launch(void* const* d_in, const int* in_sizes, int n_in,
                              void* d_out, int out_size, void* d_ws, size_t ws_size,
                              hipStream_t stream) {
    const float* x      = (const float*)d_in[0];
    const float* A      = (const float*)d_in[1];
    const float* Wih    = (const float*)d_in[2];
    const float* Whh    = (const float*)d_in[3];
    const float* bih    = (const float*)d_in[4];
    const float* bhh    = (const float*)d_in[5];
    const float* attn_w = (const float*)d_in[6];
    const float* attn_b = (const float*)d_in[7];
    const float* gnn_w  = (const float*)d_in[8];
    const float* gnn_b  = (const float*)d_in[9];
    const float* pred_w = (const float*)d_in[10];
    const float* pred_b = (const float*)d_in[11];
    float* preds = (float*)d_out;

    // ws: E16 (4MB) | ET (4MB) | coefQ (4MB) | deg (4KB)  ~= 12 MB
    _Float16* E16 = (_Float16*)d_ws;
    _Float16* ET  = E16 + (size_t)BNc * Hc;
    float* coefQ  = (float*)(ET + (size_t)BNc * Hc);
    float* deg    = coefQ + (size_t)Nc * Nc;

    hipMemsetAsync(preds, 0, (size_t)out_size * sizeof(float), stream);
    hipMemsetAsync(deg, 0, Nc * sizeof(float), stream);

    lstm_attn_kernel<<<BNc / 128, 256, 0, stream>>>(x, Wih, Whh, bih, bhh,
                                                    attn_w, attn_b, E16, ET);
    coefq_kernel<<<256, 256, 0, stream>>>(A, gnn_w, gnn_b, coefQ, deg);
    gnn_pred_kernel<<<Bc * (Nc / 64), 256, 0, stream>>>(E16, ET, coefQ, deg,
                                                        pred_w, pred_b, preds);
}